// Round 1
// baseline (1174.592 us; speedup 1.0000x reference)
//
#include <hip/hip_runtime.h>

// Problem constants (fixed by the reference):
//   z: [16,1024,256] fp32 -> N=16384 rows, D=256
//   embedding: [8192,256] fp32 -> K=8192 codes
//   out = [ z_q (4194304 f32) | loss (1 f32) | indices (16384, stored as f32) ]
#define N_ROWS   16384
#define DIM      256
#define N_CODES  8192
#define ZQ_ELEMS 4194304

#define TM 64      // rows per block
#define TN 128     // codes per tile
#define BK 64      // d-chunk
#define ZPAD 68    // z_t row stride (floats): keeps float4 alignment, breaks pow2 banks
#define EPAD 129   // e_t row stride (floats): conflict-free strided b32 reads

// ---------------- Kernel A: e_norms + zero the loss slot ----------------
__global__ void vq_prep(const float* __restrict__ emb,
                        float* __restrict__ norms,
                        float* __restrict__ loss_ptr) {
    if (blockIdx.x == 0 && threadIdx.x == 0) *loss_ptr = 0.0f;
    int gtid = blockIdx.x * blockDim.x + threadIdx.x;
    int wid  = gtid >> 6;          // one wave per code
    int lane = gtid & 63;
    if (wid < N_CODES) {
        const float4* row = (const float4*)(emb + (size_t)wid * DIM);
        float4 v = row[lane];      // 64 lanes x float4 = 256 floats
        float s = v.x * v.x + v.y * v.y + v.z * v.z + v.w * v.w;
        #pragma unroll
        for (int off = 32; off > 0; off >>= 1) s += __shfl_down(s, off, 64);
        if (lane == 0) norms[wid] = s;
    }
}

// ---------------- Kernel B: distances + argmin + z_q + loss ----------------
__global__ __launch_bounds__(512, 2)
void vq_main(const float* __restrict__ z,
             const float* __restrict__ emb,
             const float* __restrict__ norms,
             float* __restrict__ zq_out,
             float* __restrict__ loss_out,
             float* __restrict__ idx_out) {
    __shared__ __align__(16) float z_t[BK][ZPAD];   // 17,408 B   [d][row]
    __shared__ __align__(16) float e_t[BK][EPAD];   // 33,024 B   [d][code]
    __shared__ int best_s[TM];                      // 256 B

    const int t   = threadIdx.x;      // 0..511
    const int tx  = t & 31;           // code group: codes tx + 32*j
    const int ty  = t >> 5;           // row group (0..15): rows ty*4 + j
    const int sd  = t & 63;           // staging: d within chunk
    const int sr  = t >> 6;           // staging: row/code stripe (0..7)
    const int row0 = blockIdx.x * TM; // 256 blocks exactly cover 16384 rows

    float min_d[4];
    int   min_i[4];
    #pragma unroll
    for (int j = 0; j < 4; ++j) { min_d[j] = 3.4e38f; min_i[j] = 0; }

    for (int kt = 0; kt < N_CODES / TN; ++kt) {     // 64 code tiles
        float acc[4][4];
        #pragma unroll
        for (int a = 0; a < 4; ++a)
            #pragma unroll
            for (int b = 0; b < 4; ++b) acc[a][b] = 0.0f;

        for (int dk = 0; dk < DIM / BK; ++dk) {     // 4 d-chunks
            __syncthreads();
            // stage z chunk transposed: z_t[d][r]
            #pragma unroll
            for (int p = 0; p < 8; ++p) {
                int r = sr + p * 8;
                z_t[sd][r] = z[(size_t)(row0 + r) * DIM + dk * BK + sd];
            }
            // stage e chunk transposed: e_t[d][c]
            #pragma unroll
            for (int p = 0; p < 16; ++p) {
                int c = sr + p * 8;
                e_t[sd][c] = emb[(size_t)(kt * TN + c) * DIM + dk * BK + sd];
            }
            __syncthreads();

            #pragma unroll 8
            for (int d = 0; d < BK; ++d) {
                float4 zv = *(const float4*)&z_t[d][ty * 4];
                float e0 = e_t[d][tx];
                float e1 = e_t[d][tx + 32];
                float e2 = e_t[d][tx + 64];
                float e3 = e_t[d][tx + 96];
                acc[0][0] += zv.x * e0; acc[0][1] += zv.x * e1;
                acc[0][2] += zv.x * e2; acc[0][3] += zv.x * e3;
                acc[1][0] += zv.y * e0; acc[1][1] += zv.y * e1;
                acc[1][2] += zv.y * e2; acc[1][3] += zv.y * e3;
                acc[2][0] += zv.z * e0; acc[2][1] += zv.z * e1;
                acc[2][2] += zv.z * e2; acc[2][3] += zv.z * e3;
                acc[3][0] += zv.w * e0; acc[3][1] += zv.w * e1;
                acc[3][2] += zv.w * e2; acc[3][3] += zv.w * e3;
            }
        }

        // finalize tile: dist = ||e||^2 - 2*dot (||z||^2 constant per row)
        #pragma unroll
        for (int jc = 0; jc < 4; ++jc) {
            int cg = kt * TN + tx + 32 * jc;
            float nrm = norms[cg];
            #pragma unroll
            for (int jr = 0; jr < 4; ++jr) {
                float dist = nrm - 2.0f * acc[jr][jc];
                if (dist < min_d[jr]) { min_d[jr] = dist; min_i[jr] = cg; }
            }
        }
    }

    // cross-thread argmin reduction (32 threads share each row); reuse e_t
    __syncthreads();
    float* dist_s = &e_t[0][0];           // 64*32 floats
    int*   idx_s  = ((int*)&e_t[0][0]) + TM * 32;
    #pragma unroll
    for (int jr = 0; jr < 4; ++jr) {
        int rl = ty * 4 + jr;
        dist_s[rl * 32 + tx] = min_d[jr];
        idx_s [rl * 32 + tx] = min_i[jr];
    }
    __syncthreads();
    if (t < TM) {
        int rl = t;
        float bd = dist_s[rl * 32];
        int   bi = idx_s [rl * 32];
        for (int j = 1; j < 32; ++j) {
            float d2 = dist_s[rl * 32 + j];
            int   i2 = idx_s [rl * 32 + j];
            if (d2 < bd || (d2 == bd && i2 < bi)) { bd = d2; bi = i2; }
        }
        best_s[rl] = bi;
        idx_out[row0 + rl] = (float)bi;   // indices stored as f32 in flat out
    }
    __syncthreads();

    // epilogue: z_q gather + loss partial. wave w handles rows w*8..w*8+7
    const int wave = t >> 6, lane = t & 63;
    float lsum = 0.0f;
    #pragma unroll
    for (int rr = 0; rr < 8; ++rr) {
        int rl = wave * 8 + rr;
        int rg = row0 + rl;
        int code = best_s[rl];
        float4 ev = *(const float4*)(emb + (size_t)code * DIM + lane * 4);
        float4 zv = *(const float4*)(z   + (size_t)rg   * DIM + lane * 4);
        float dx = ev.x - zv.x, dy = ev.y - zv.y;
        float dz = ev.z - zv.z, dw = ev.w - zv.w;
        lsum += dx * dx + dy * dy + dz * dz + dw * dw;
        *(float4*)(zq_out + (size_t)rg * DIM + lane * 4) = ev;
    }
    #pragma unroll
    for (int off = 32; off > 0; off >>= 1) lsum += __shfl_down(lsum, off, 64);
    if (lane == 0) atomicAdd(loss_out, lsum * (1.25f / (float)ZQ_ELEMS));
}

extern "C" void kernel_launch(void* const* d_in, const int* in_sizes, int n_in,
                              void* d_out, int out_size, void* d_ws, size_t ws_size,
                              hipStream_t stream) {
    const float* z   = (const float*)d_in[0];
    const float* emb = (const float*)d_in[1];
    float* out   = (float*)d_out;
    float* zq    = out;                // 4,194,304
    float* loss  = out + ZQ_ELEMS;     // 1
    float* idx   = out + ZQ_ELEMS + 1; // 16,384
    float* norms = (float*)d_ws;       // 8192 floats scratch

    vq_prep<<<N_CODES * 64 / 256, 256, 0, stream>>>(emb, norms, loss);
    vq_main<<<N_ROWS / TM, 512, 0, stream>>>(z, emb, norms, zq, loss, idx);
}

// Round 2
// 370.230 us; speedup vs baseline: 3.1726x; 3.1726x over previous
//
#include <hip/hip_runtime.h>

// z: [16,1024,256] fp32 -> N=16384 rows, D=256
// embedding: [8192,256] fp32 -> K=8192 codes
// out = [ z_q (4194304 f32) | loss (1 f32) | indices (16384, stored as f32) ]
#define N_ROWS   16384
#define DIM      256
#define N_CODES  8192
#define ZQ_ELEMS 4194304

typedef _Float16 f16x8 __attribute__((ext_vector_type(8)));
typedef _Float16 f16x4 __attribute__((ext_vector_type(4)));
typedef float    f32x16 __attribute__((ext_vector_type(16)));

// ---------------- workspace layout (bytes) ----------------
// z_hi: 8 MB | z_lo: 8 MB | e_hi: 4 MB | e_lo: 4 MB | norms 32 KB | pd 128 KB | pi 128 KB
#define WS_ZHI 0
#define WS_ZLO (8388608)
#define WS_EHI (16777216)
#define WS_ELO (20971520)
#define WS_NRM (25165824)
#define WS_PD  (25198592)
#define WS_PI  (25329664)

// ---------------- prep: split E into f16 hi/lo + exact fp32 norms ----------------
__global__ void vq_prep_e(const float* __restrict__ emb,
                          _Float16* __restrict__ eh, _Float16* __restrict__ el,
                          float* __restrict__ norms, float* __restrict__ loss_ptr) {
    if (blockIdx.x == 0 && threadIdx.x == 0) *loss_ptr = 0.0f;
    int gt = blockIdx.x * 256 + threadIdx.x;
    int code = gt >> 6, lane = gt & 63;
    float4 v = *(const float4*)(emb + (size_t)code * DIM + lane * 4);
    float xs[4] = {v.x, v.y, v.z, v.w};
    f16x4 hh, ll;
    float s = 0.0f;
    #pragma unroll
    for (int i = 0; i < 4; ++i) {
        _Float16 h = (_Float16)xs[i];
        hh[i] = h;
        ll[i] = (_Float16)(xs[i] - (float)h);
        s += xs[i] * xs[i];
    }
    *(f16x4*)(eh + (size_t)code * DIM + lane * 4) = hh;
    *(f16x4*)(el + (size_t)code * DIM + lane * 4) = ll;
    #pragma unroll
    for (int off = 32; off > 0; off >>= 1) s += __shfl_down(s, off, 64);
    if (lane == 0) norms[code] = s;
}

// ---------------- prep: split Z into f16 hi/lo ----------------
__global__ void vq_prep_z(const float* __restrict__ z,
                          _Float16* __restrict__ zh, _Float16* __restrict__ zl) {
    int gt = blockIdx.x * 256 + threadIdx.x;
    int row = gt >> 6, lane = gt & 63;
    float4 v = *(const float4*)(z + (size_t)row * DIM + lane * 4);
    float xs[4] = {v.x, v.y, v.z, v.w};
    f16x4 hh, ll;
    #pragma unroll
    for (int i = 0; i < 4; ++i) {
        _Float16 h = (_Float16)xs[i];
        hh[i] = h;
        ll[i] = (_Float16)(xs[i] - (float)h);
    }
    *(f16x4*)(zh + (size_t)row * DIM + lane * 4) = hh;
    *(f16x4*)(zl + (size_t)row * DIM + lane * 4) = ll;
}

// ---------------- main: f16x3 MFMA distance GEMM + per-split argmin ----------------
// grid 512 = 256 row-blocks x 2 code-splits. block: 64 rows x (8 kt x 512 codes).
// wave tile 64x128 = 2x4 MFMA tiles of 32x32x16. E tile in LDS (stride 40 halves),
// A frags per-lane from global (L1-hot). Dynamic LDS 81920 B.
#define ESTR 40            // LDS halves per E row (32 + 8 pad)
__global__ __launch_bounds__(256, 2)
void vq_main(const _Float16* __restrict__ zh, const _Float16* __restrict__ zl,
             const _Float16* __restrict__ ehg, const _Float16* __restrict__ elg,
             const float* __restrict__ norms,
             float* __restrict__ pd, int* __restrict__ pi) {
    extern __shared__ char smem[];
    _Float16* eh = (_Float16*)smem;                 // [512][40] halves = 40960 B
    _Float16* el = (_Float16*)(smem + 40960);       // [512][40] halves
    float*    cd  = (float*)smem;                   // [64][129]  (overlays eh/el)
    int*      ci  = (int*)(smem + 33024);           // [64][129]
    float*    cd2 = (float*)(smem + 66048);         // [4][64]
    int*      ci2 = (int*)(smem + 67072);           // [4][64]

    const int tid = threadIdx.x;
    const int w   = tid >> 6;        // wave 0..3
    const int L   = tid & 63;
    const int lo5 = L & 31;
    const int hi1 = L >> 5;
    const int s    = blockIdx.x & 1;           // code split
    const int row0 = (blockIdx.x >> 1) * 64;   // 64 rows per block
    const int codeS = s * 4096;

    // per-lane A-frag base (halves): row = row0+lo5 (+rt*32), k-sub = hi1*8
    const int zbase = (row0 + lo5) * DIM + hi1 * 8;

    float rd = 3.4e38f;  int ri = 0;   // running (dist, idx) for row 'tid' (tid<64)

    for (int kt = 0; kt < 8; ++kt) {
        const int code0 = codeS + kt * 512;
        const int cbase = code0 + w * 128;

        f32x16 acc[2][4];
        #pragma unroll
        for (int rt = 0; rt < 2; ++rt)
            #pragma unroll
            for (int ct = 0; ct < 4; ++ct)
                #pragma unroll
                for (int e = 0; e < 16; ++e) acc[rt][ct][e] = 0.0f;

        for (int dk = 0; dk < 8; ++dk) {
            __syncthreads();   // prior frag reads / cand scans done
            // ---- stage E chunk (512 codes x 32 halves, hi+lo) ----
            #pragma unroll
            for (int half = 0; half < 2; ++half) {
                f16x8 th[4], tl[4];
                #pragma unroll
                for (int p = 0; p < 4; ++p) {
                    int slot = tid + (half * 4 + p) * 256;    // 0..2047
                    int r = slot >> 2, sl = slot & 3;
                    int goff = (code0 + r) * DIM + dk * 32 + sl * 8;
                    th[p] = *(const f16x8*)(ehg + goff);
                    tl[p] = *(const f16x8*)(elg + goff);
                }
                #pragma unroll
                for (int p = 0; p < 4; ++p) {
                    int slot = tid + (half * 4 + p) * 256;
                    int r = slot >> 2, sl = slot & 3;
                    int loff = r * ESTR + sl * 8;
                    *(f16x8*)(eh + loff) = th[p];
                    *(f16x8*)(el + loff) = tl[p];
                }
            }
            __syncthreads();

            // ---- compute: 2 ksteps of 16 ----
            #pragma unroll
            for (int ks = 0; ks < 2; ++ks) {
                const int koff = dk * 32 + ks * 16;
                f16x8 ah[2], al[2];
                #pragma unroll
                for (int rt = 0; rt < 2; ++rt) {
                    ah[rt] = *(const f16x8*)(zh + zbase + rt * 32 * DIM + koff);
                    al[rt] = *(const f16x8*)(zl + zbase + rt * 32 * DIM + koff);
                }
                f16x8 bh[4], bl[4];
                const int eoff = (w * 128 + lo5) * ESTR + hi1 * 8 + ks * 16;
                #pragma unroll
                for (int ct = 0; ct < 4; ++ct) {
                    bh[ct] = *(f16x8*)(eh + eoff + ct * 32 * ESTR);
                    bl[ct] = *(f16x8*)(el + eoff + ct * 32 * ESTR);
                }
                #pragma unroll
                for (int rt = 0; rt < 2; ++rt)
                    #pragma unroll
                    for (int ct = 0; ct < 4; ++ct) {
                        acc[rt][ct] = __builtin_amdgcn_mfma_f32_32x32x16_f16(ah[rt], bh[ct], acc[rt][ct], 0, 0, 0);
                        acc[rt][ct] = __builtin_amdgcn_mfma_f32_32x32x16_f16(ah[rt], bl[ct], acc[rt][ct], 0, 0, 0);
                        acc[rt][ct] = __builtin_amdgcn_mfma_f32_32x32x16_f16(al[rt], bh[ct], acc[rt][ct], 0, 0, 0);
                    }
            }
        }

        // ---- distances + fold over 4 col-tiles (keep lowest code on ties) ----
        float nrm[4];
        #pragma unroll
        for (int ct = 0; ct < 4; ++ct) nrm[ct] = norms[cbase + ct * 32 + lo5];

        float fd[2][16]; int fi[2][16];
        #pragma unroll
        for (int rt = 0; rt < 2; ++rt)
            #pragma unroll
            for (int reg = 0; reg < 16; ++reg) {
                float bd = nrm[0] - 2.0f * acc[rt][0][reg];
                int   bi = cbase + lo5;
                #pragma unroll
                for (int ct = 1; ct < 4; ++ct) {
                    float d = nrm[ct] - 2.0f * acc[rt][ct][reg];
                    if (d < bd) { bd = d; bi = cbase + ct * 32 + lo5; }
                }
                fd[rt][reg] = bd; fi[rt][reg] = bi;
            }

        __syncthreads();   // all MFMA frag reads done -> reuse LDS for candidates
        #pragma unroll
        for (int rt = 0; rt < 2; ++rt)
            #pragma unroll
            for (int reg = 0; reg < 16; ++reg) {
                int rloc = rt * 32 + (reg & 3) + ((reg >> 2) << 3) + (hi1 << 2);
                cd[rloc * 129 + w * 32 + lo5] = fd[rt][reg];
                ci[rloc * 129 + w * 32 + lo5] = fi[rt][reg];
            }
        __syncthreads();

        // phase 1: thread (r,q) scans its wave-quarter (codes ascending)
        {
            int r = tid & 63, q = tid >> 6;
            int base = r * 129 + q * 32;
            float bd = cd[base]; int bi = ci[base];
            #pragma unroll 8
            for (int j = 1; j < 32; ++j) {
                float d = cd[base + j];
                if (d < bd) { bd = d; bi = ci[base + j]; }
            }
            cd2[q * 64 + r] = bd; ci2[q * 64 + r] = bi;
        }
        __syncthreads();

        // phase 2: row owner merges 4 quarters into running min
        if (tid < 64) {
            #pragma unroll
            for (int q = 0; q < 4; ++q) {
                float d = cd2[q * 64 + tid];
                if (d < rd) { rd = d; ri = ci2[q * 64 + tid]; }
            }
        }
    }

    if (tid < 64) {
        pd[(row0 + tid) * 2 + s] = rd;
        pi[(row0 + tid) * 2 + s] = ri;
    }
}

// ---------------- epilogue: merge splits, write idx, gather z_q, loss ----------------
__global__ __launch_bounds__(512)
void vq_epilogue(const float* __restrict__ z, const float* __restrict__ emb,
                 const float* __restrict__ pd, const int* __restrict__ pi,
                 float* __restrict__ zq_out, float* __restrict__ loss_out,
                 float* __restrict__ idx_out) {
    const int wave = threadIdx.x >> 6, lane = threadIdx.x & 63;
    float lsum = 0.0f;
    #pragma unroll
    for (int rr = 0; rr < 8; ++rr) {
        int rg = blockIdx.x * 64 + wave * 8 + rr;
        float d0 = pd[rg * 2], d1 = pd[rg * 2 + 1];
        int code = (d1 < d0) ? pi[rg * 2 + 1] : pi[rg * 2];  // tie -> lower split
        if (lane == 0) idx_out[rg] = (float)code;
        float4 ev = *(const float4*)(emb + (size_t)code * DIM + lane * 4);
        float4 zv = *(const float4*)(z   + (size_t)rg   * DIM + lane * 4);
        float dx = ev.x - zv.x, dy = ev.y - zv.y;
        float dz = ev.z - zv.z, dw = ev.w - zv.w;
        lsum += dx * dx + dy * dy + dz * dz + dw * dw;
        *(float4*)(zq_out + (size_t)rg * DIM + lane * 4) = ev;
    }
    #pragma unroll
    for (int off = 32; off > 0; off >>= 1) lsum += __shfl_down(lsum, off, 64);
    if (lane == 0) atomicAdd(loss_out, lsum * (1.25f / (float)ZQ_ELEMS));
}

extern "C" void kernel_launch(void* const* d_in, const int* in_sizes, int n_in,
                              void* d_out, int out_size, void* d_ws, size_t ws_size,
                              hipStream_t stream) {
    const float* z   = (const float*)d_in[0];
    const float* emb = (const float*)d_in[1];
    float* out  = (float*)d_out;
    float* zq   = out;
    float* loss = out + ZQ_ELEMS;
    float* idx  = out + ZQ_ELEMS + 1;

    char* ws = (char*)d_ws;
    _Float16* zh = (_Float16*)(ws + WS_ZHI);
    _Float16* zl = (_Float16*)(ws + WS_ZLO);
    _Float16* eh = (_Float16*)(ws + WS_EHI);
    _Float16* el = (_Float16*)(ws + WS_ELO);
    float* norms = (float*)(ws + WS_NRM);
    float* pd    = (float*)(ws + WS_PD);
    int*   pi    = (int*)(ws + WS_PI);

    static bool attr_set = false;
    if (!attr_set) {
        hipFuncSetAttribute((const void*)vq_main,
                            hipFuncAttributeMaxDynamicSharedMemorySize, 81920);
        attr_set = true;
    }

    vq_prep_e<<<N_CODES / 4, 256, 0, stream>>>(emb, eh, el, norms, loss);
    vq_prep_z<<<N_ROWS / 4, 256, 0, stream>>>(z, zh, zl);
    vq_main<<<512, 256, 81920, stream>>>(zh, zl, eh, el, norms, pd, pi);
    vq_epilogue<<<256, 512, 0, stream>>>(z, emb, pd, pi, zq, loss, idx);
}